// Round 1
// baseline (290.667 us; speedup 1.0000x reference)
//
#include <hip/hip_runtime.h>
#include <hip/hip_bf16.h>

// ---------------------------------------------------------------------------
// MultiHeadAttention: x[2,2048,1024] fp32, W{q,k,v,o}[1024,1024] fp32 ([out,in])
// out = softmax((xWq^T)(xWk^T)^T / 8) (xWv^T) Wo^T   (per 16 heads of dk=64)
// Strategy: cast everything to bf16, MFMA 16x16x32 pipeline, fp32 accum.
// ---------------------------------------------------------------------------

typedef __attribute__((ext_vector_type(8))) short bf16x8;
typedef __attribute__((ext_vector_type(4))) float f32x4;

#define D_MODEL 1024
#define NHEADS  16
#define DK      64
#define BATCH   2
#define SEQ     2048
#define MROWS   4096   // BATCH*SEQ

__device__ __forceinline__ unsigned short f2bf(float f) {
    unsigned u = __builtin_bit_cast(unsigned, f);
    u = (u + 0x7FFFu + ((u >> 16) & 1u)) >> 16;
    return (unsigned short)u;
}

__device__ __forceinline__ void gload16(const void* g, void* l) {
    __builtin_amdgcn_global_load_lds(
        (const __attribute__((address_space(1))) unsigned int*)g,
        (__attribute__((address_space(3))) unsigned int*)l, 16, 0, 0);
}

// ---------------------------------------------------------------------------
// fp32 -> bf16 casts: blocks [0,2048) = x (4M elems), then 512 blocks per weight
// ---------------------------------------------------------------------------
__global__ __launch_bounds__(256) void cast_all(
    const float* __restrict__ x,
    const float* __restrict__ wq, const float* __restrict__ wk,
    const float* __restrict__ wv, const float* __restrict__ wo,
    short* __restrict__ xb,
    short* __restrict__ wqb, short* __restrict__ wkb,
    short* __restrict__ wvb, short* __restrict__ wob)
{
    int bid = blockIdx.x;
    const float* src; short* dst; long base;
    if (bid < 2048) { src = x; dst = xb; base = (long)bid * 2048; }
    else {
        int k = (bid - 2048) >> 9;
        int r = (bid - 2048) & 511;
        base = (long)r * 2048;
        src = (k == 0) ? wq : (k == 1) ? wk : (k == 2) ? wv : wo;
        dst = (k == 0) ? wqb : (k == 1) ? wkb : (k == 2) ? wvb : wob;
    }
    long off = base + (long)threadIdx.x * 8;
    float4 a = *(const float4*)&src[off];
    float4 b = *(const float4*)&src[off + 4];
    union { unsigned short us[8]; uint4 u; } pk;
    pk.us[0] = f2bf(a.x); pk.us[1] = f2bf(a.y); pk.us[2] = f2bf(a.z); pk.us[3] = f2bf(a.w);
    pk.us[4] = f2bf(b.x); pk.us[5] = f2bf(b.y); pk.us[6] = f2bf(b.z); pk.us[7] = f2bf(b.w);
    *(uint4*)&dst[off] = pk.u;
}

// ---------------------------------------------------------------------------
// C[M=4096, N=1024] = A[4096,1024] @ W[1024,1024]^T   (bf16 in, fp32 acc)
// 128x128 tile, BK=32, 4 waves (2x2 of 64x64), global_load_lds staging.
// ---------------------------------------------------------------------------
template<int OUT_BF16>
__global__ __launch_bounds__(256) void gemm_bt(
    const short* __restrict__ A, const short* __restrict__ W, void* __restrict__ Cout)
{
    __shared__ short At[128 * 32];
    __shared__ short Bt[128 * 32];
    const int tid = threadIdx.x;
    const int w = tid >> 6, l = tid & 63, lg = l >> 4, ln = l & 15;
    const int wr = w >> 1, wc = w & 1;
    const long row0 = (long)blockIdx.y * 128;
    const long col0 = (long)blockIdx.x * 128;
    const char* Ab = (const char*)A;
    const char* Wb = (const char*)W;

    f32x4 acc[4][4] = {};

    for (int k0 = 0; k0 < 1024; k0 += 32) {
        __syncthreads();
#pragma unroll
        for (int c = 0; c < 2; ++c) {
            int lin = (c * 4 + w) * 1024 + l * 16;   // byte offset in 8KB tile
            int r = lin >> 6, cb = lin & 63;         // 64 B per row (32 bf16)
            gload16(Ab + (size_t)(row0 + r) * 2048 + (size_t)k0 * 2 + cb,
                    (char*)At + (c * 4 + w) * 1024);
            gload16(Wb + (size_t)(col0 + r) * 2048 + (size_t)k0 * 2 + cb,
                    (char*)Bt + (c * 4 + w) * 1024);
        }
        __syncthreads();

        bf16x8 af[4], bfr[4];
#pragma unroll
        for (int i = 0; i < 4; ++i)
            af[i] = *(const bf16x8*)&At[(wr * 64 + i * 16 + ln) * 32 + lg * 8];
#pragma unroll
        for (int j = 0; j < 4; ++j)
            bfr[j] = *(const bf16x8*)&Bt[(wc * 64 + j * 16 + ln) * 32 + lg * 8];
#pragma unroll
        for (int i = 0; i < 4; ++i)
#pragma unroll
            for (int j = 0; j < 4; ++j)
                acc[i][j] = __builtin_amdgcn_mfma_f32_16x16x32_bf16(af[i], bfr[j], acc[i][j], 0, 0, 0);
    }

#pragma unroll
    for (int i = 0; i < 4; ++i)
#pragma unroll
        for (int j = 0; j < 4; ++j)
#pragma unroll
            for (int rr = 0; rr < 4; ++rr) {
                long grow = row0 + wr * 64 + i * 16 + lg * 4 + rr;
                long gcol = col0 + wc * 64 + j * 16 + ln;
                float v = acc[i][j][rr];
                if (OUT_BF16)
                    ((short*)Cout)[grow * 1024 + gcol] = (short)f2bf(v);
                else
                    ((float*)Cout)[grow * 1024 + gcol] = v;
            }
}

// ---------------------------------------------------------------------------
// V[4096,1024] -> VT[1024,4096]  (bf16 tiled transpose)
// ---------------------------------------------------------------------------
__global__ __launch_bounds__(256) void transpose_bf16(
    const short* __restrict__ V, short* __restrict__ VT)
{
    __shared__ short t[64][66];
    const int tid = threadIdx.x;
    const int r = tid >> 2, c4 = (tid & 3) * 16;
    const long m0 = (long)blockIdx.y * 64;   // row tile in V (0..4095)
    const long n0 = (long)blockIdx.x * 64;   // col tile in V (0..1023)
#pragma unroll
    for (int j = 0; j < 2; ++j) {
        bf16x8 v = *(const bf16x8*)&V[(m0 + r) * 1024 + n0 + c4 + j * 8];
#pragma unroll
        for (int e = 0; e < 8; ++e) t[c4 + j * 8 + e][r] = v[e];
    }
    __syncthreads();
#pragma unroll
    for (int j = 0; j < 2; ++j) {
        bf16x8 v;
#pragma unroll
        for (int e = 0; e < 8; ++e) v[e] = t[r][c4 + j * 8 + e];
        *(bf16x8*)&VT[(n0 + r) * 4096 + m0 + c4 + j * 8] = v;
    }
}

// ---------------------------------------------------------------------------
// Flash attention. Grid: (qtile 0..31, b*h 0..31). 256 thr = 4 waves,
// each wave owns 16 q-rows. KV tiles of 64. All LDS tiles are [rows][128B]
// with XOR swizzle  byte ^= ((row&7)<<4)  (T2; pre-swizzled global source
// for global_load_lds, swizzled ds_read/ds_write on consumption).
// ---------------------------------------------------------------------------
__global__ __launch_bounds__(256) void attn_fwd(
    const short* __restrict__ Q, const short* __restrict__ K,
    const short* __restrict__ VT, short* __restrict__ O)
{
    __shared__ short Kt[64 * 64];        // K tile  [kv=64][dk=64]
    __shared__ short Vt[64 * 64];        // VT tile [d=64][kv=64]
    __shared__ short Pt[4 * 16 * 64];    // per-wave P [16][64]

    const int tid = threadIdx.x;
    const int w = tid >> 6, l = tid & 63, lg = l >> 4, ln = l & 15;
    const int bh = blockIdx.y, b = bh >> 4, h = bh & 15;
    const int qt = blockIdx.x;
    const long qrow0 = (long)b * SEQ + (long)qt * 64;

    // Q fragments, kept in registers for the whole kernel
    bf16x8 qf[2];
#pragma unroll
    for (int kk = 0; kk < 2; ++kk)
        qf[kk] = *(const bf16x8*)&Q[(qrow0 + w * 16 + ln) * 1024 + h * 64 + kk * 32 + lg * 8];

    f32x4 o[4] = {};
    float m_run[4] = { -1e30f, -1e30f, -1e30f, -1e30f };
    float l_run[4] = {};

    const char* Kb  = (const char*)K;
    const char* VTb = (const char*)VT;

    for (int t = 0; t < 32; ++t) {
        __syncthreads();
        // stage K tile and VT tile (8 KB each); dest linear, source pre-swizzled
#pragma unroll
        for (int c = 0; c < 2; ++c) {
            int lin = (c * 4 + w) * 1024 + l * 16;           // physical byte in tile
            int r = lin >> 7;                                // row (128 B rows)
            int cb = (lin & 127) ^ ((r & 7) << 4);           // logical col byte
            gload16(Kb + (size_t)(b * SEQ + t * 64 + r) * 2048 + h * 128 + cb,
                    (char*)Kt + (c * 4 + w) * 1024);
            gload16(VTb + (size_t)(h * 64 + r) * 8192 + (size_t)(b * SEQ + t * 64) * 2 + cb,
                    (char*)Vt + (c * 4 + w) * 1024);
        }
        __syncthreads();

        // ---- S = Q K^T  (16 q-rows x 64 kv-cols per wave) ----
        f32x4 s[4] = {};
#pragma unroll
        for (int nb = 0; nb < 4; ++nb) {
            int row = nb * 16 + ln;
#pragma unroll
            for (int kk = 0; kk < 2; ++kk) {
                int cb = (kk * 64 + lg * 16) ^ ((row & 7) << 4);
                bf16x8 kf = *(const bf16x8*)((const char*)Kt + row * 128 + cb);
                s[nb] = __builtin_amdgcn_mfma_f32_16x16x32_bf16(qf[kk], kf, s[nb], 0, 0, 0);
            }
        }
#pragma unroll
        for (int nb = 0; nb < 4; ++nb) s[nb] *= 0.125f;   // 1/sqrt(dk)

        // ---- online softmax (rows live on 16-lane groups) ----
        float p[4][4];
#pragma unroll
        for (int i = 0; i < 4; ++i) {
            float mx = fmaxf(fmaxf(s[0][i], s[1][i]), fmaxf(s[2][i], s[3][i]));
#pragma unroll
            for (int msk = 1; msk < 16; msk <<= 1)
                mx = fmaxf(mx, __shfl_xor(mx, msk, 64));
            float mn = fmaxf(m_run[i], mx);
            float fac = __expf(m_run[i] - mn);
            m_run[i] = mn;
            float sum = 0.f;
#pragma unroll
            for (int nb = 0; nb < 4; ++nb) {
                float pv = __expf(s[nb][i] - mn);
                p[nb][i] = pv;
                sum += pv;
            }
#pragma unroll
            for (int msk = 1; msk < 16; msk <<= 1)
                sum += __shfl_xor(sum, msk, 64);
            l_run[i] = l_run[i] * fac + sum;
            o[0][i] *= fac; o[1][i] *= fac; o[2][i] *= fac; o[3][i] *= fac;
        }

        // ---- P -> bf16 -> per-wave LDS (swizzled) ----
#pragma unroll
        for (int nb = 0; nb < 4; ++nb)
#pragma unroll
            for (int i = 0; i < 4; ++i) {
                int row = lg * 4 + i;
                int cb = ((nb * 16 + ln) * 2) ^ ((row & 7) << 4);
                *(short*)((char*)Pt + w * 2048 + row * 128 + cb) = (short)f2bf(p[nb][i]);
            }

        // ---- O += P V  ----
        bf16x8 pa[2];
#pragma unroll
        for (int kk = 0; kk < 2; ++kk) {
            int cb = (kk * 64 + lg * 16) ^ ((ln & 7) << 4);
            pa[kk] = *(const bf16x8*)((const char*)Pt + w * 2048 + ln * 128 + cb);
        }
#pragma unroll
        for (int nb = 0; nb < 4; ++nb) {
            int row = nb * 16 + ln;
#pragma unroll
            for (int kk = 0; kk < 2; ++kk) {
                int cb = (kk * 64 + lg * 16) ^ ((row & 7) << 4);
                bf16x8 vf = *(const bf16x8*)((const char*)Vt + row * 128 + cb);
                o[nb] = __builtin_amdgcn_mfma_f32_16x16x32_bf16(pa[kk], vf, o[nb], 0, 0, 0);
            }
        }
    }

    // ---- normalize + store (bf16, [B*S, H*DK] layout) ----
#pragma unroll
    for (int nb = 0; nb < 4; ++nb)
#pragma unroll
        for (int i = 0; i < 4; ++i) {
            float v = o[nb][i] / l_run[i];
            O[(qrow0 + w * 16 + lg * 4 + i) * 1024 + h * 64 + nb * 16 + ln] = (short)f2bf(v);
        }
}

// ---------------------------------------------------------------------------
extern "C" void kernel_launch(void* const* d_in, const int* in_sizes, int n_in,
                              void* d_out, int out_size, void* d_ws, size_t ws_size,
                              hipStream_t stream)
{
    const float* x  = (const float*)d_in[0];
    const float* wq = (const float*)d_in[1];
    const float* wk = (const float*)d_in[2];
    const float* wv = (const float*)d_in[3];
    const float* wo = (const float*)d_in[4];
    float* out = (float*)d_out;
    char* ws = (char*)d_ws;

    const size_t MB = 1024 * 1024;
    short* Xb  = (short*)(ws);                 // 8 MB  (4096x1024 bf16)
    short* Wqb = (short*)(ws + 8  * MB);       // 2 MB
    short* Wkb = (short*)(ws + 10 * MB);
    short* Wvb = (short*)(ws + 12 * MB);
    short* Wob = (short*)(ws + 14 * MB);
    short* Qb  = (short*)(ws + 16 * MB);       // 8 MB
    short* Kb  = (short*)(ws + 24 * MB);       // 8 MB
    short* Vb  = (short*)(ws + 32 * MB);       // 8 MB
    short* VTb = (short*)(ws + 40 * MB);       // 8 MB (1024x4096)
    short* Ab  = (short*)(ws + 48 * MB);       // 8 MB attn output

    cast_all<<<4096, 256, 0, stream>>>(x, wq, wk, wv, wo, Xb, Wqb, Wkb, Wvb, Wob);

    dim3 ggrid(8, 32);   // N/128, M/128
    gemm_bt<1><<<ggrid, 256, 0, stream>>>(Xb, Wqb, Qb);
    gemm_bt<1><<<ggrid, 256, 0, stream>>>(Xb, Wkb, Kb);
    gemm_bt<1><<<ggrid, 256, 0, stream>>>(Xb, Wvb, Vb);

    transpose_bf16<<<dim3(16, 64), 256, 0, stream>>>(Vb, VTb);

    attn_fwd<<<dim3(32, 32), 256, 0, stream>>>(Qb, Kb, VTb, Ab);

    gemm_bt<0><<<ggrid, 256, 0, stream>>>(Ab, Wob, out);
}

// Round 5
// 232.532 us; speedup vs baseline: 1.2500x; 1.2500x over previous
//
#include <hip/hip_runtime.h>
#include <hip/hip_bf16.h>

// ---------------------------------------------------------------------------
// MultiHeadAttention: x[2,2048,1024] fp32, W{q,k,v,o}[1024,1024] fp32 ([out,in])
// out = softmax((xWq^T)(xWk^T)^T / 8) (xWv^T) Wo^T   (16 heads, dk=64)
// bf16 MFMA pipeline, fp32 accum. v2b: swapped-QK in-lane softmax, exp2 domain,
// packed P writes (manual bf16 pack — __hip_bfloat162 isn't trivially
// copyable so __builtin_bit_cast on it fails), fused QKV projection GEMM.
// ---------------------------------------------------------------------------

typedef __attribute__((ext_vector_type(8))) short bf16x8;
typedef __attribute__((ext_vector_type(4))) float f32x4;

#define SEQ     2048

__device__ __forceinline__ unsigned short f2bf(float f) {
    unsigned u = __builtin_bit_cast(unsigned, f);
    u = (u + 0x7FFFu + ((u >> 16) & 1u)) >> 16;
    return (unsigned short)u;
}

__device__ __forceinline__ unsigned pack_bf2(float lo, float hi) {
    return (unsigned)f2bf(lo) | ((unsigned)f2bf(hi) << 16);
}

__device__ __forceinline__ float fexp2(float x) {
    return exp2f(x);   // maps to v_exp_f32 with -O3 fast math on amdgcn
}

__device__ __forceinline__ void gload16(const void* g, void* l) {
    __builtin_amdgcn_global_load_lds(
        (const __attribute__((address_space(1))) unsigned int*)g,
        (__attribute__((address_space(3))) unsigned int*)l, 16, 0, 0);
}

// ---------------------------------------------------------------------------
// fp32 -> bf16 casts: blocks [0,2048) = x, then 512 blocks per weight
// ---------------------------------------------------------------------------
__global__ __launch_bounds__(256) void cast_all(
    const float* __restrict__ x,
    const float* __restrict__ wq, const float* __restrict__ wk,
    const float* __restrict__ wv, const float* __restrict__ wo,
    short* __restrict__ xb,
    short* __restrict__ wqb, short* __restrict__ wkb,
    short* __restrict__ wvb, short* __restrict__ wob)
{
    int bid = blockIdx.x;
    const float* src; short* dst; long base;
    if (bid < 2048) { src = x; dst = xb; base = (long)bid * 2048; }
    else {
        int k = (bid - 2048) >> 9;
        int r = (bid - 2048) & 511;
        base = (long)r * 2048;
        src = (k == 0) ? wq : (k == 1) ? wk : (k == 2) ? wv : wo;
        dst = (k == 0) ? wqb : (k == 1) ? wkb : (k == 2) ? wvb : wob;
    }
    long off = base + (long)threadIdx.x * 8;
    float4 a = *(const float4*)&src[off];
    float4 b = *(const float4*)&src[off + 4];
    union { unsigned short us[8]; uint4 u; } pk;
    pk.us[0] = f2bf(a.x); pk.us[1] = f2bf(a.y); pk.us[2] = f2bf(a.z); pk.us[3] = f2bf(a.w);
    pk.us[4] = f2bf(b.x); pk.us[5] = f2bf(b.y); pk.us[6] = f2bf(b.z); pk.us[7] = f2bf(b.w);
    *(uint4*)&dst[off] = pk.u;
}

// ---------------------------------------------------------------------------
// Fused QKV: C[4096,1024*3] = A @ {Wq,Wk,Wv}^T, Q scaled by 0.125*log2(e).
// 128x128 tile, BK=32, 4 waves. grid (24, 32) = 768 blocks (3/CU).
// ---------------------------------------------------------------------------
__global__ __launch_bounds__(256) void gemm_qkv(
    const short* __restrict__ A,
    const short* __restrict__ W0, const short* __restrict__ W1, const short* __restrict__ W2,
    short* __restrict__ D0, short* __restrict__ D1, short* __restrict__ D2)
{
    __shared__ short At[128 * 32];
    __shared__ short Bt[128 * 32];
    const int tid = threadIdx.x;
    const int w = tid >> 6, l = tid & 63, lg = l >> 4, ln = l & 15;
    const int wr = w >> 1, wc = w & 1;
    const int reg = blockIdx.x >> 3;
    const short* W = (reg == 0) ? W0 : (reg == 1) ? W1 : W2;
    short* Dst     = (reg == 0) ? D0 : (reg == 1) ? D1 : D2;
    const float sc = (reg == 0) ? 0.18033688011112042f : 1.0f;  // 0.125*log2(e)
    const long col0 = (long)(blockIdx.x & 7) * 128;
    const long row0 = (long)blockIdx.y * 128;
    const char* Ab = (const char*)A;
    const char* Wb = (const char*)W;

    f32x4 acc[4][4] = {};

    for (int k0 = 0; k0 < 1024; k0 += 32) {
        __syncthreads();
#pragma unroll
        for (int c = 0; c < 2; ++c) {
            int lin = (c * 4 + w) * 1024 + l * 16;
            int r = lin >> 6, cb = lin & 63;
            gload16(Ab + (size_t)(row0 + r) * 2048 + (size_t)k0 * 2 + cb,
                    (char*)At + (c * 4 + w) * 1024);
            gload16(Wb + (size_t)(col0 + r) * 2048 + (size_t)k0 * 2 + cb,
                    (char*)Bt + (c * 4 + w) * 1024);
        }
        __syncthreads();

        bf16x8 af[4], bfr[4];
#pragma unroll
        for (int i = 0; i < 4; ++i)
            af[i] = *(const bf16x8*)&At[(wr * 64 + i * 16 + ln) * 32 + lg * 8];
#pragma unroll
        for (int j = 0; j < 4; ++j)
            bfr[j] = *(const bf16x8*)&Bt[(wc * 64 + j * 16 + ln) * 32 + lg * 8];
#pragma unroll
        for (int i = 0; i < 4; ++i)
#pragma unroll
            for (int j = 0; j < 4; ++j)
                acc[i][j] = __builtin_amdgcn_mfma_f32_16x16x32_bf16(af[i], bfr[j], acc[i][j], 0, 0, 0);
    }

#pragma unroll
    for (int i = 0; i < 4; ++i)
#pragma unroll
        for (int j = 0; j < 4; ++j)
#pragma unroll
            for (int rr = 0; rr < 4; ++rr) {
                long grow = row0 + wr * 64 + i * 16 + lg * 4 + rr;
                long gcol = col0 + wc * 64 + j * 16 + ln;
                Dst[grow * 1024 + gcol] = (short)f2bf(acc[i][j][rr] * sc);
            }
}

// ---------------------------------------------------------------------------
// C[4096,1024] = A @ W^T, fp32 out (output projection)
// ---------------------------------------------------------------------------
__global__ __launch_bounds__(256) void gemm_bt_f32(
    const short* __restrict__ A, const short* __restrict__ W, float* __restrict__ Cout)
{
    __shared__ short At[128 * 32];
    __shared__ short Bt[128 * 32];
    const int tid = threadIdx.x;
    const int w = tid >> 6, l = tid & 63, lg = l >> 4, ln = l & 15;
    const int wr = w >> 1, wc = w & 1;
    const long row0 = (long)blockIdx.y * 128;
    const long col0 = (long)blockIdx.x * 128;
    const char* Ab = (const char*)A;
    const char* Wb = (const char*)W;

    f32x4 acc[4][4] = {};

    for (int k0 = 0; k0 < 1024; k0 += 32) {
        __syncthreads();
#pragma unroll
        for (int c = 0; c < 2; ++c) {
            int lin = (c * 4 + w) * 1024 + l * 16;
            int r = lin >> 6, cb = lin & 63;
            gload16(Ab + (size_t)(row0 + r) * 2048 + (size_t)k0 * 2 + cb,
                    (char*)At + (c * 4 + w) * 1024);
            gload16(Wb + (size_t)(col0 + r) * 2048 + (size_t)k0 * 2 + cb,
                    (char*)Bt + (c * 4 + w) * 1024);
        }
        __syncthreads();

        bf16x8 af[4], bfr[4];
#pragma unroll
        for (int i = 0; i < 4; ++i)
            af[i] = *(const bf16x8*)&At[(wr * 64 + i * 16 + ln) * 32 + lg * 8];
#pragma unroll
        for (int j = 0; j < 4; ++j)
            bfr[j] = *(const bf16x8*)&Bt[(wc * 64 + j * 16 + ln) * 32 + lg * 8];
#pragma unroll
        for (int i = 0; i < 4; ++i)
#pragma unroll
            for (int j = 0; j < 4; ++j)
                acc[i][j] = __builtin_amdgcn_mfma_f32_16x16x32_bf16(af[i], bfr[j], acc[i][j], 0, 0, 0);
    }

#pragma unroll
    for (int i = 0; i < 4; ++i)
#pragma unroll
        for (int j = 0; j < 4; ++j)
#pragma unroll
            for (int rr = 0; rr < 4; ++rr) {
                long grow = row0 + wr * 64 + i * 16 + lg * 4 + rr;
                long gcol = col0 + wc * 64 + j * 16 + ln;
                Cout[grow * 1024 + gcol] = acc[i][j][rr];
            }
}

// ---------------------------------------------------------------------------
// V[4096,1024] -> VT[1024,4096]  (bf16 tiled transpose)
// ---------------------------------------------------------------------------
__global__ __launch_bounds__(256) void transpose_bf16(
    const short* __restrict__ V, short* __restrict__ VT)
{
    __shared__ short t[64][66];
    const int tid = threadIdx.x;
    const int r = tid >> 2, c4 = (tid & 3) * 16;
    const long m0 = (long)blockIdx.y * 64;
    const long n0 = (long)blockIdx.x * 64;
#pragma unroll
    for (int j = 0; j < 2; ++j) {
        bf16x8 v = *(const bf16x8*)&V[(m0 + r) * 1024 + n0 + c4 + j * 8];
#pragma unroll
        for (int e = 0; e < 8; ++e) t[c4 + j * 8 + e][r] = v[e];
    }
    __syncthreads();
#pragma unroll
    for (int j = 0; j < 2; ++j) {
        bf16x8 v;
#pragma unroll
        for (int e = 0; e < 8; ++e) v[e] = t[r][c4 + j * 8 + e];
        *(bf16x8*)&VT[(n0 + r) * 4096 + m0 + c4 + j * 8] = v;
    }
}

// ---------------------------------------------------------------------------
// Flash attention v2. Grid (32 qtiles, 32 b*h), 4 waves x 16 q-rows, KVBLK=64.
// Q pre-scaled by 0.125*log2e -> softmax in exp2 domain.
// Swapped QK^T: s^T = mfma(kf, qf) puts a q-row's scores in-lane
// (lane: q=ln, kv = nb*16 + lg*4 + i)  -> row reduce = in-lane + 2 shfls.
// P packed to bf16 pairs, 4x ds_write_b64, read back as A-frag for PV.
// LDS tiles swizzled: byte ^= ((row&7)<<4); staging via pre-swizzled source.
// ---------------------------------------------------------------------------
__global__ __launch_bounds__(256) void attn_fwd(
    const short* __restrict__ Q, const short* __restrict__ K,
    const short* __restrict__ VT, short* __restrict__ O)
{
    __shared__ short Kt[64 * 64];        // K tile  [kv=64][dk=64]
    __shared__ short Vt[64 * 64];        // VT tile [d=64][kv=64]
    __shared__ short Pt[4 * 16 * 64];    // per-wave P [q=16][kv=64]

    const int tid = threadIdx.x;
    const int w = tid >> 6, l = tid & 63, lg = l >> 4, ln = l & 15;
    const int bh = blockIdx.y, b = bh >> 4, h = bh & 15;
    const int qt = blockIdx.x;
    const long qrow0 = (long)b * SEQ + (long)qt * 64;

    bf16x8 qf[2];
#pragma unroll
    for (int kk = 0; kk < 2; ++kk)
        qf[kk] = *(const bf16x8*)&Q[(qrow0 + w * 16 + ln) * 1024 + h * 64 + kk * 32 + lg * 8];

    f32x4 o[4] = {};
    float m_run = -1e30f, l_run = 0.f;

    const char* Kb  = (const char*)K;
    const char* VTb = (const char*)VT;

    for (int t = 0; t < 32; ++t) {
        __syncthreads();
#pragma unroll
        for (int c = 0; c < 2; ++c) {
            int lin = (c * 4 + w) * 1024 + l * 16;           // physical byte in tile
            int r = lin >> 7;                                // 128 B rows
            int cb = (lin & 127) ^ ((r & 7) << 4);           // logical col byte
            gload16(Kb + (size_t)(b * SEQ + t * 64 + r) * 2048 + h * 128 + cb,
                    (char*)Kt + (c * 4 + w) * 1024);
            gload16(VTb + (size_t)(h * 64 + r) * 8192 + (size_t)(b * SEQ + t * 64) * 2 + cb,
                    (char*)Vt + (c * 4 + w) * 1024);
        }
        __syncthreads();

        // ---- S^T = K Q^T : lane holds s[nb][i] = S[q=ln][kv=nb*16+lg*4+i] ----
        f32x4 s[4] = {};
#pragma unroll
        for (int nb = 0; nb < 4; ++nb) {
            int row = nb * 16 + ln;
#pragma unroll
            for (int kk = 0; kk < 2; ++kk) {
                int cb = (kk * 64 + lg * 16) ^ ((row & 7) << 4);
                bf16x8 kf = *(const bf16x8*)((const char*)Kt + row * 128 + cb);
                s[nb] = __builtin_amdgcn_mfma_f32_16x16x32_bf16(kf, qf[kk], s[nb], 0, 0, 0);
            }
        }

        // ---- online softmax, per-lane (16 kv values of row q=ln) ----
        float mx = s[0][0];
#pragma unroll
        for (int nb = 0; nb < 4; ++nb)
#pragma unroll
            for (int i = 0; i < 4; ++i) mx = fmaxf(mx, s[nb][i]);
        mx = fmaxf(mx, __shfl_xor(mx, 16, 64));
        mx = fmaxf(mx, __shfl_xor(mx, 32, 64));
        float mn = fmaxf(m_run, mx);
        float fac = fexp2(m_run - mn);
        m_run = mn;
        float p[4][4];
        float sum = 0.f;
#pragma unroll
        for (int nb = 0; nb < 4; ++nb)
#pragma unroll
            for (int i = 0; i < 4; ++i) {
                float pv = fexp2(s[nb][i] - mn);
                p[nb][i] = pv;
                sum += pv;
            }
        sum += __shfl_xor(sum, 16, 64);
        sum += __shfl_xor(sum, 32, 64);
        l_run = l_run * fac + sum;

        // ---- pack P (bf16 pairs), one b64 write per nb ----
#pragma unroll
        for (int nb = 0; nb < 4; ++nb) {
            unsigned pk0 = pack_bf2(p[nb][0], p[nb][1]);
            unsigned pk1 = pack_bf2(p[nb][2], p[nb][3]);
            int cb = (32 * nb + 8 * lg) ^ ((ln & 7) << 4);
            *(uint2*)((char*)Pt + w * 2048 + ln * 128 + cb) = uint2{ pk0, pk1 };
        }

        // ---- rescale O by fac of its own rows (rows = lg*4+i) ----
        float facr[4];
#pragma unroll
        for (int i = 0; i < 4; ++i)
            facr[i] = __shfl(fac, 16 * lg + lg * 4 + i, 64);
#pragma unroll
        for (int nb = 0; nb < 4; ++nb)
#pragma unroll
            for (int i = 0; i < 4; ++i) o[nb][i] *= facr[i];

        // ---- O += P V ----
        bf16x8 pa[2];
#pragma unroll
        for (int kk = 0; kk < 2; ++kk) {
            int cb = (kk * 64 + lg * 16) ^ ((ln & 7) << 4);
            pa[kk] = *(const bf16x8*)((const char*)Pt + w * 2048 + ln * 128 + cb);
        }
#pragma unroll
        for (int nb = 0; nb < 4; ++nb) {
            int row = nb * 16 + ln;
#pragma unroll
            for (int kk = 0; kk < 2; ++kk) {
                int cb = (kk * 64 + lg * 16) ^ ((row & 7) << 4);
                bf16x8 vf = *(const bf16x8*)((const char*)Vt + row * 128 + cb);
                o[nb] = __builtin_amdgcn_mfma_f32_16x16x32_bf16(pa[kk], vf, o[nb], 0, 0, 0);
            }
        }
    }

    // ---- normalize + store ----
    float rl[4];
#pragma unroll
    for (int i = 0; i < 4; ++i)
        rl[i] = 1.0f / __shfl(l_run, 16 * lg + lg * 4 + i, 64);
#pragma unroll
    for (int nb = 0; nb < 4; ++nb)
#pragma unroll
        for (int i = 0; i < 4; ++i) {
            float v = o[nb][i] * rl[i];
            O[(qrow0 + w * 16 + lg * 4 + i) * 1024 + h * 64 + nb * 16 + ln] = (short)f2bf(v);
        }
}

// ---------------------------------------------------------------------------
extern "C" void kernel_launch(void* const* d_in, const int* in_sizes, int n_in,
                              void* d_out, int out_size, void* d_ws, size_t ws_size,
                              hipStream_t stream)
{
    const float* x  = (const float*)d_in[0];
    const float* wq = (const float*)d_in[1];
    const float* wk = (const float*)d_in[2];
    const float* wv = (const float*)d_in[3];
    const float* wo = (const float*)d_in[4];
    float* out = (float*)d_out;
    char* ws = (char*)d_ws;

    const size_t MB = 1024 * 1024;
    short* Xb  = (short*)(ws);                 // 8 MB
    short* Wqb = (short*)(ws + 8  * MB);       // 2 MB
    short* Wkb = (short*)(ws + 10 * MB);
    short* Wvb = (short*)(ws + 12 * MB);
    short* Wob = (short*)(ws + 14 * MB);
    short* Qb  = (short*)(ws + 16 * MB);       // 8 MB (pre-scaled by 0.125*log2e)
    short* Kb  = (short*)(ws + 24 * MB);       // 8 MB
    short* Vb  = (short*)(ws + 32 * MB);       // 8 MB
    short* VTb = (short*)(ws + 40 * MB);       // 8 MB (1024x4096)
    short* Ab  = (short*)(ws + 48 * MB);       // 8 MB attn output

    cast_all<<<4096, 256, 0, stream>>>(x, wq, wk, wv, wo, Xb, Wqb, Wkb, Wvb, Wob);

    gemm_qkv<<<dim3(24, 32), 256, 0, stream>>>(Xb, Wqb, Wkb, Wvb, Qb, Kb, Vb);

    transpose_bf16<<<dim3(16, 64), 256, 0, stream>>>(Vb, VTb);

    attn_fwd<<<dim3(32, 32), 256, 0, stream>>>(Qb, Kb, VTb, Ab);

    gemm_bt_f32<<<dim3(8, 32), 256, 0, stream>>>(Ab, Wob, out);
}

// Round 8
// 222.486 us; speedup vs baseline: 1.3065x; 1.0452x over previous
//
#include <hip/hip_runtime.h>
#include <hip/hip_bf16.h>

// ---------------------------------------------------------------------------
// MultiHeadAttention: x[2,2048,1024] fp32, W{q,k,v,o}[1024,1024] fp32 ([out,in])
// out = softmax((xWq^T)(xWk^T)^T / 8) (xWv^T) Wo^T   (16 heads, dk=64)
// v3: split-KV flash attention (2 halves + merge kernel), conflict-free
// per-wave P layout [nb][lg][q][4] (linear writes, imm-offset reads),
// defer-max rescale (THR=8 in log2 domain). GEMMs unchanged from v2.
// (3rd resubmit: rounds 6 and 7 were broker acquisition timeouts)
// ---------------------------------------------------------------------------

typedef __attribute__((ext_vector_type(8))) short bf16x8;
typedef __attribute__((ext_vector_type(4))) float f32x4;

#define SEQ     2048

__device__ __forceinline__ unsigned short f2bf(float f) {
    unsigned u = __builtin_bit_cast(unsigned, f);
    u = (u + 0x7FFFu + ((u >> 16) & 1u)) >> 16;
    return (unsigned short)u;
}

__device__ __forceinline__ float bf2f(unsigned short v) {
    return __builtin_bit_cast(float, ((unsigned)v) << 16);
}

__device__ __forceinline__ unsigned pack_bf2(float lo, float hi) {
    return (unsigned)f2bf(lo) | ((unsigned)f2bf(hi) << 16);
}

__device__ __forceinline__ float fexp2(float x) {
    return exp2f(x);
}

__device__ __forceinline__ void gload16(const void* g, void* l) {
    __builtin_amdgcn_global_load_lds(
        (const __attribute__((address_space(1))) unsigned int*)g,
        (__attribute__((address_space(3))) unsigned int*)l, 16, 0, 0);
}

// ---------------------------------------------------------------------------
// fp32 -> bf16 casts: blocks [0,2048) = x, then 512 blocks per weight
// ---------------------------------------------------------------------------
__global__ __launch_bounds__(256) void cast_all(
    const float* __restrict__ x,
    const float* __restrict__ wq, const float* __restrict__ wk,
    const float* __restrict__ wv, const float* __restrict__ wo,
    short* __restrict__ xb,
    short* __restrict__ wqb, short* __restrict__ wkb,
    short* __restrict__ wvb, short* __restrict__ wob)
{
    int bid = blockIdx.x;
    const float* src; short* dst; long base;
    if (bid < 2048) { src = x; dst = xb; base = (long)bid * 2048; }
    else {
        int k = (bid - 2048) >> 9;
        int r = (bid - 2048) & 511;
        base = (long)r * 2048;
        src = (k == 0) ? wq : (k == 1) ? wk : (k == 2) ? wv : wo;
        dst = (k == 0) ? wqb : (k == 1) ? wkb : (k == 2) ? wvb : wob;
    }
    long off = base + (long)threadIdx.x * 8;
    float4 a = *(const float4*)&src[off];
    float4 b = *(const float4*)&src[off + 4];
    union { unsigned short us[8]; uint4 u; } pk;
    pk.us[0] = f2bf(a.x); pk.us[1] = f2bf(a.y); pk.us[2] = f2bf(a.z); pk.us[3] = f2bf(a.w);
    pk.us[4] = f2bf(b.x); pk.us[5] = f2bf(b.y); pk.us[6] = f2bf(b.z); pk.us[7] = f2bf(b.w);
    *(uint4*)&dst[off] = pk.u;
}

// ---------------------------------------------------------------------------
// Fused QKV: C[4096,1024*3] = A @ {Wq,Wk,Wv}^T, Q scaled by 0.125*log2(e).
// 128x128 tile, BK=32, 4 waves. grid (24, 32) = 768 blocks (3/CU).
// ---------------------------------------------------------------------------
__global__ __launch_bounds__(256) void gemm_qkv(
    const short* __restrict__ A,
    const short* __restrict__ W0, const short* __restrict__ W1, const short* __restrict__ W2,
    short* __restrict__ D0, short* __restrict__ D1, short* __restrict__ D2)
{
    __shared__ short At[128 * 32];
    __shared__ short Bt[128 * 32];
    const int tid = threadIdx.x;
    const int w = tid >> 6, l = tid & 63, lg = l >> 4, ln = l & 15;
    const int wr = w >> 1, wc = w & 1;
    const int reg = blockIdx.x >> 3;
    const short* W = (reg == 0) ? W0 : (reg == 1) ? W1 : W2;
    short* Dst     = (reg == 0) ? D0 : (reg == 1) ? D1 : D2;
    const float sc = (reg == 0) ? 0.18033688011112042f : 1.0f;  // 0.125*log2(e)
    const long col0 = (long)(blockIdx.x & 7) * 128;
    const long row0 = (long)blockIdx.y * 128;
    const char* Ab = (const char*)A;
    const char* Wb = (const char*)W;

    f32x4 acc[4][4] = {};

    for (int k0 = 0; k0 < 1024; k0 += 32) {
        __syncthreads();
#pragma unroll
        for (int c = 0; c < 2; ++c) {
            int lin = (c * 4 + w) * 1024 + l * 16;
            int r = lin >> 6, cb = lin & 63;
            gload16(Ab + (size_t)(row0 + r) * 2048 + (size_t)k0 * 2 + cb,
                    (char*)At + (c * 4 + w) * 1024);
            gload16(Wb + (size_t)(col0 + r) * 2048 + (size_t)k0 * 2 + cb,
                    (char*)Bt + (c * 4 + w) * 1024);
        }
        __syncthreads();

        bf16x8 af[4], bfr[4];
#pragma unroll
        for (int i = 0; i < 4; ++i)
            af[i] = *(const bf16x8*)&At[(wr * 64 + i * 16 + ln) * 32 + lg * 8];
#pragma unroll
        for (int j = 0; j < 4; ++j)
            bfr[j] = *(const bf16x8*)&Bt[(wc * 64 + j * 16 + ln) * 32 + lg * 8];
#pragma unroll
        for (int i = 0; i < 4; ++i)
#pragma unroll
            for (int j = 0; j < 4; ++j)
                acc[i][j] = __builtin_amdgcn_mfma_f32_16x16x32_bf16(af[i], bfr[j], acc[i][j], 0, 0, 0);
    }

#pragma unroll
    for (int i = 0; i < 4; ++i)
#pragma unroll
        for (int j = 0; j < 4; ++j)
#pragma unroll
            for (int rr = 0; rr < 4; ++rr) {
                long grow = row0 + wr * 64 + i * 16 + lg * 4 + rr;
                long gcol = col0 + wc * 64 + j * 16 + ln;
                Dst[grow * 1024 + gcol] = (short)f2bf(acc[i][j][rr] * sc);
            }
}

// ---------------------------------------------------------------------------
// C[4096,1024] = A @ W^T, fp32 out (output projection)
// ---------------------------------------------------------------------------
__global__ __launch_bounds__(256) void gemm_bt_f32(
    const short* __restrict__ A, const short* __restrict__ W, float* __restrict__ Cout)
{
    __shared__ short At[128 * 32];
    __shared__ short Bt[128 * 32];
    const int tid = threadIdx.x;
    const int w = tid >> 6, l = tid & 63, lg = l >> 4, ln = l & 15;
    const int wr = w >> 1, wc = w & 1;
    const long row0 = (long)blockIdx.y * 128;
    const long col0 = (long)blockIdx.x * 128;
    const char* Ab = (const char*)A;
    const char* Wb = (const char*)W;

    f32x4 acc[4][4] = {};

    for (int k0 = 0; k0 < 1024; k0 += 32) {
        __syncthreads();
#pragma unroll
        for (int c = 0; c < 2; ++c) {
            int lin = (c * 4 + w) * 1024 + l * 16;
            int r = lin >> 6, cb = lin & 63;
            gload16(Ab + (size_t)(row0 + r) * 2048 + (size_t)k0 * 2 + cb,
                    (char*)At + (c * 4 + w) * 1024);
            gload16(Wb + (size_t)(col0 + r) * 2048 + (size_t)k0 * 2 + cb,
                    (char*)Bt + (c * 4 + w) * 1024);
        }
        __syncthreads();

        bf16x8 af[4], bfr[4];
#pragma unroll
        for (int i = 0; i < 4; ++i)
            af[i] = *(const bf16x8*)&At[(wr * 64 + i * 16 + ln) * 32 + lg * 8];
#pragma unroll
        for (int j = 0; j < 4; ++j)
            bfr[j] = *(const bf16x8*)&Bt[(wc * 64 + j * 16 + ln) * 32 + lg * 8];
#pragma unroll
        for (int i = 0; i < 4; ++i)
#pragma unroll
            for (int j = 0; j < 4; ++j)
                acc[i][j] = __builtin_amdgcn_mfma_f32_16x16x32_bf16(af[i], bfr[j], acc[i][j], 0, 0, 0);
    }

#pragma unroll
    for (int i = 0; i < 4; ++i)
#pragma unroll
        for (int j = 0; j < 4; ++j)
#pragma unroll
            for (int rr = 0; rr < 4; ++rr) {
                long grow = row0 + wr * 64 + i * 16 + lg * 4 + rr;
                long gcol = col0 + wc * 64 + j * 16 + ln;
                Cout[grow * 1024 + gcol] = acc[i][j][rr];
            }
}

// ---------------------------------------------------------------------------
// V[4096,1024] -> VT[1024,4096]  (bf16 tiled transpose)
// ---------------------------------------------------------------------------
__global__ __launch_bounds__(256) void transpose_bf16(
    const short* __restrict__ V, short* __restrict__ VT)
{
    __shared__ short t[64][66];
    const int tid = threadIdx.x;
    const int r = tid >> 2, c4 = (tid & 3) * 16;
    const long m0 = (long)blockIdx.y * 64;
    const long n0 = (long)blockIdx.x * 64;
#pragma unroll
    for (int j = 0; j < 2; ++j) {
        bf16x8 v = *(const bf16x8*)&V[(m0 + r) * 1024 + n0 + c4 + j * 8];
#pragma unroll
        for (int e = 0; e < 8; ++e) t[c4 + j * 8 + e][r] = v[e];
    }
    __syncthreads();
#pragma unroll
    for (int j = 0; j < 2; ++j) {
        bf16x8 v;
#pragma unroll
        for (int e = 0; e < 8; ++e) v[e] = t[r][c4 + j * 8 + e];
        *(bf16x8*)&VT[(n0 + r) * 4096 + m0 + c4 + j * 8] = v;
    }
}

// ---------------------------------------------------------------------------
// Flash attention v3, split-KV. Grid (64 = qt*2+half, 32 b*h), 4 waves,
// 16 q-rows/wave, KVBLK=64, 16 KV tiles per block (half of 32).
// Swapped QK^T (in-lane softmax, exp2 domain), defer-max THR=8.
// Per-wave P LDS layout [nb=4][lg=4][q=16][4elem]: write = base + lane*8
// (linear, conflict-free), read = one base + imm offsets {0,128,1024,1152}.
// Outputs unnormalized O (bf16) + (m,l) per row for the merge pass.
// ---------------------------------------------------------------------------
__global__ __launch_bounds__(256, 6) void attn_part(
    const short* __restrict__ Q, const short* __restrict__ K,
    const short* __restrict__ VT,
    short* __restrict__ OP0, short* __restrict__ OP1,
    float2* __restrict__ ML0, float2* __restrict__ ML1)
{
    __shared__ short Kt[64 * 64];        // K tile  [kv=64][dk=64], swizzled
    __shared__ short Vt[64 * 64];        // VT tile [d=64][kv=64], swizzled
    __shared__ short Pt[4 * 1024];       // per-wave P, 2KB each

    const int tid = threadIdx.x;
    const int w = tid >> 6, l = tid & 63, lg = l >> 4, ln = l & 15;
    const int bh = blockIdx.y, b = bh >> 4, h = bh & 15;
    const int qt = blockIdx.x >> 1, half = blockIdx.x & 1;
    const long qrow0 = (long)b * SEQ + (long)qt * 64;

    short*  __restrict__ OPh = half ? OP1 : OP0;
    float2* __restrict__ MLh = half ? ML1 : ML0;

    bf16x8 qf[2];
#pragma unroll
    for (int kk = 0; kk < 2; ++kk)
        qf[kk] = *(const bf16x8*)&Q[(qrow0 + w * 16 + ln) * 1024 + h * 64 + kk * 32 + lg * 8];

    f32x4 o[4] = {};
    float m_run = -1e30f, l_run = 0.f;

    const char* Kb  = (const char*)K;
    const char* VTb = (const char*)VT;

    // P LDS addresses (loop-invariant)
    char*       Pw = (char*)Pt + w * 2048 + l * 8;
    const char* Pr = (char*)Pt + w * 2048 + (lg >> 1) * 512 + (lg & 1) * 256 + ln * 8;

    for (int t = half * 16; t < half * 16 + 16; ++t) {
        __syncthreads();
#pragma unroll
        for (int c = 0; c < 2; ++c) {
            int lin = (c * 4 + w) * 1024 + l * 16;           // physical byte in tile
            int r = lin >> 7;                                // 128 B rows
            int cb = (lin & 127) ^ ((r & 7) << 4);           // logical col byte
            gload16(Kb + (size_t)(b * SEQ + t * 64 + r) * 2048 + h * 128 + cb,
                    (char*)Kt + (c * 4 + w) * 1024);
            gload16(VTb + (size_t)(h * 64 + r) * 8192 + (size_t)(b * SEQ + t * 64) * 2 + cb,
                    (char*)Vt + (c * 4 + w) * 1024);
        }
        __syncthreads();

        // ---- S^T = K Q^T : lane holds s[nb][i] = S[q=ln][kv=nb*16+lg*4+i] ----
        f32x4 s[4] = {};
#pragma unroll
        for (int nb = 0; nb < 4; ++nb) {
            int row = nb * 16 + ln;
#pragma unroll
            for (int kk = 0; kk < 2; ++kk) {
                int cb = (kk * 64 + lg * 16) ^ ((row & 7) << 4);
                bf16x8 kf = *(const bf16x8*)((const char*)Kt + row * 128 + cb);
                s[nb] = __builtin_amdgcn_mfma_f32_16x16x32_bf16(kf, qf[kk], s[nb], 0, 0, 0);
            }
        }

        // ---- online softmax with defer-max (THR=8 in log2 units) ----
        float mx = s[0][0];
#pragma unroll
        for (int nb = 0; nb < 4; ++nb)
#pragma unroll
            for (int i = 0; i < 4; ++i) mx = fmaxf(mx, s[nb][i]);
        mx = fmaxf(mx, __shfl_xor(mx, 16, 64));
        mx = fmaxf(mx, __shfl_xor(mx, 32, 64));

        if (__any(mx > m_run + 8.0f)) {
            float mn = fmaxf(m_run, mx);
            float fac = fexp2(m_run - mn);
            m_run = mn;
            l_run *= fac;
            float facr[4];
#pragma unroll
            for (int i = 0; i < 4; ++i)
                facr[i] = __shfl(fac, 16 * lg + lg * 4 + i, 64);
#pragma unroll
            for (int nb = 0; nb < 4; ++nb)
#pragma unroll
                for (int i = 0; i < 4; ++i) o[nb][i] *= facr[i];
        }

        float p[4][4];
        float sum = 0.f;
#pragma unroll
        for (int nb = 0; nb < 4; ++nb)
#pragma unroll
            for (int i = 0; i < 4; ++i) {
                float pv = fexp2(s[nb][i] - m_run);
                p[nb][i] = pv;
                sum += pv;
            }
        sum += __shfl_xor(sum, 16, 64);
        sum += __shfl_xor(sum, 32, 64);
        l_run += sum;

        // ---- P -> bf16 -> per-wave LDS (linear, conflict-free) ----
#pragma unroll
        for (int nb = 0; nb < 4; ++nb) {
            uint2 pw = { pack_bf2(p[nb][0], p[nb][1]), pack_bf2(p[nb][2], p[nb][3]) };
            *(uint2*)(Pw + nb * 512) = pw;
        }

        // ---- O += P V ----
        bf16x8 pa[2];
#pragma unroll
        for (int kk = 0; kk < 2; ++kk) {
            uint2 d0 = *(const uint2*)(Pr + kk * 1024);
            uint2 d1 = *(const uint2*)(Pr + kk * 1024 + 128);
            uint4 u4 = { d0.x, d0.y, d1.x, d1.y };
            pa[kk] = __builtin_bit_cast(bf16x8, u4);
        }
#pragma unroll
        for (int nb = 0; nb < 4; ++nb) {
            int row = nb * 16 + ln;
#pragma unroll
            for (int kk = 0; kk < 2; ++kk) {
                int cb = (kk * 64 + lg * 16) ^ ((row & 7) << 4);
                bf16x8 vf = *(const bf16x8*)((const char*)Vt + row * 128 + cb);
                o[nb] = __builtin_amdgcn_mfma_f32_16x16x32_bf16(pa[kk], vf, o[nb], 0, 0, 0);
            }
        }
    }

    // ---- store unnormalized partials ----
    const long Rbase = (long)bh * SEQ + qt * 64 + w * 16;
#pragma unroll
    for (int nb = 0; nb < 4; ++nb)
#pragma unroll
        for (int i = 0; i < 4; ++i) {
            long R = Rbase + lg * 4 + i;
            OPh[R * 64 + nb * 16 + ln] = (short)f2bf(o[nb][i]);
        }
    if (lg == 0)
        MLh[Rbase + ln] = float2{ m_run, l_run };
}

// ---------------------------------------------------------------------------
// Merge the two KV halves: O = (w0*o0 + w1*o1) / (w0*l0 + w1*l1),
// w_h = exp2(m_h - max(m0,m1)). Writes attn output Ab [B*S, H*DK] bf16.
// ---------------------------------------------------------------------------
__global__ __launch_bounds__(256) void attn_merge(
    const short* __restrict__ O0, const short* __restrict__ O1,
    const float2* __restrict__ ML0, const float2* __restrict__ ML1,
    short* __restrict__ Ab)
{
    int gid = blockIdx.x * 256 + threadIdx.x;   // [0, 524288)
    int R = gid >> 3, d0 = (gid & 7) * 8;
    float2 a = ML0[R];
    float2 c = ML1[R];
    float M = fmaxf(a.x, c.x);
    float w0 = fexp2(a.x - M), w1 = fexp2(c.x - M);
    float rden = 1.0f / (w0 * a.y + w1 * c.y);
    bf16x8 v0 = *(const bf16x8*)&O0[(long)R * 64 + d0];
    bf16x8 v1 = *(const bf16x8*)&O1[(long)R * 64 + d0];
    int bh = R >> 11, s = R & 2047, b = bh >> 4, h = bh & 15;
    union { unsigned short us[8]; uint4 u; } pk;
#pragma unroll
    for (int e = 0; e < 8; ++e) {
        float f0 = bf2f((unsigned short)v0[e]);
        float f1 = bf2f((unsigned short)v1[e]);
        pk.us[e] = f2bf((w0 * f0 + w1 * f1) * rden);
    }
    *(uint4*)&Ab[((long)(b * 2048 + s)) * 1024 + h * 64 + d0] = pk.u;
}

// ---------------------------------------------------------------------------
extern "C" void kernel_launch(void* const* d_in, const int* in_sizes, int n_in,
                              void* d_out, int out_size, void* d_ws, size_t ws_size,
                              hipStream_t stream)
{
    const float* x  = (const float*)d_in[0];
    const float* wq = (const float*)d_in[1];
    const float* wk = (const float*)d_in[2];
    const float* wv = (const float*)d_in[3];
    const float* wo = (const float*)d_in[4];
    float* out = (float*)d_out;
    char* ws = (char*)d_ws;

    const size_t MB = 1024 * 1024;
    // Phase-1 buffers
    short* Xb  = (short*)(ws);                 // [0,8)   x bf16; dead after gemm_qkv
    short* Wqb = (short*)(ws + 8  * MB);       // [8,10)  dead after gemm_qkv
    short* Wkb = (short*)(ws + 10 * MB);       // [10,12) dead after gemm_qkv
    short* Wvb = (short*)(ws + 12 * MB);       // [12,14) dead after gemm_qkv
    short* Wob = (short*)(ws + 14 * MB);       // [14,16) live until gemm_bt_f32
    short* Qb  = (short*)(ws + 16 * MB);       // [16,24) pre-scaled by 0.125*log2e
    short* Kb  = (short*)(ws + 24 * MB);       // [24,32)
    short* Vb  = (short*)(ws + 32 * MB);       // [32,40) dead after transpose
    short* VTb = (short*)(ws + 40 * MB);       // [40,48) 1024x4096
    short* Ab  = (short*)(ws + 48 * MB);       // [48,56) attn output
    // Phase-2 (attn partials) — recycle dead regions
    short*  OP0 = (short*)(ws);                        // [0,8)   over Xb
    float2* ML0 = (float2*)(ws + 8 * MB);              // [8,8.5) over Wqb
    float2* ML1 = (float2*)(ws + 8 * MB + 512 * 1024); // [8.5,9) over Wqb
    short*  OP1 = (short*)(ws + 32 * MB);              // [32,40) over Vb

    cast_all<<<4096, 256, 0, stream>>>(x, wq, wk, wv, wo, Xb, Wqb, Wkb, Wvb, Wob);

    gemm_qkv<<<dim3(24, 32), 256, 0, stream>>>(Xb, Wqb, Wkb, Wvb, Qb, Kb, Vb);

    transpose_bf16<<<dim3(16, 64), 256, 0, stream>>>(Vb, VTb);

    attn_part<<<dim3(64, 32), 256, 0, stream>>>(Qb, Kb, VTb, OP0, OP1, ML0, ML1);

    attn_merge<<<2048, 256, 0, stream>>>(OP0, OP1, ML0, ML1, Ab);

    gemm_bt_f32<<<dim3(8, 32), 256, 0, stream>>>(Ab, Wob, out);
}